// Round 2
// baseline (766.784 us; speedup 1.0000x reference)
//
#include <hip/hip_runtime.h>

#define NN   4096
#define DD   128
#define RR   8
#define OUTD 128
#define BB   4096

typedef unsigned short ushort_t;
typedef __attribute__((ext_vector_type(8))) short short8;
typedef __attribute__((ext_vector_type(4))) float floatx4;

__device__ __forceinline__ ushort_t f2bf(float f) {
  union { float f; unsigned int u; } v; v.f = f;
  unsigned int u = v.u;
  return (ushort_t)((u + 0x7fffu + ((u >> 16) & 1u)) >> 16);  // RNE
}

__device__ __forceinline__ unsigned int pk2(float x, float y) {
  union { float f; unsigned int u; } a, b;
  a.f = x; b.f = y;
  const unsigned int ua = a.u + 0x8000u;
  const unsigned int ub = b.u + 0x8000u;
  return __builtin_amdgcn_perm(ub, ua, 0x07060302u);
}

__device__ __forceinline__ short8 pack8(floatx4 a, floatx4 b) {
  union { unsigned int u[4]; short8 s; } r;
  r.u[0] = pk2(a[0], a[1]); r.u[1] = pk2(a[2], a[3]);
  r.u[2] = pk2(b[0], b[1]); r.u[3] = pk2(b[2], b[3]);
  return r.s;
}

// ---------------------------------------------------------------------------
// Kernel 0: build compacted row list = unique(head_idx ∪ tail_idx).
// 1 block, 1024 threads. flags cleared in-kernel (ws is poisoned each iter).
// Compaction order arbitrary (LDS atomic counter) — consistent via inv[].
// ---------------------------------------------------------------------------
__global__ __launch_bounds__(1024) void build_rows(const int* __restrict__ hidx,
                                                   const int* __restrict__ tidx,
                                                   int* __restrict__ cnt,
                                                   int* __restrict__ rows,
                                                   int* __restrict__ inv,
                                                   int* __restrict__ flags) {
  __shared__ int lcnt;
  const int t = threadIdx.x;
  if (t == 0) lcnt = 0;
  #pragma unroll
  for (int j = 0; j < 4; ++j) flags[t + j * 1024] = 0;
  __syncthreads();
  #pragma unroll
  for (int j = 0; j < 4; ++j) {
    flags[hidx[t + j * 1024]] = 1;   // benign races: all write 1
    flags[tidx[t + j * 1024]] = 1;
  }
  __syncthreads();
  #pragma unroll
  for (int j = 0; j < 4; ++j) {
    const int rrow = t + j * 1024;
    if (flags[rrow]) {
      const int p = atomicAdd(&lcnt, 1);
      rows[p]   = rrow;
      inv[rrow] = p;
    }
  }
  __syncthreads();
  if (t == 0) *cnt = lcnt;
}

// ---------------------------------------------------------------------------
// Kernel A: Wt[r][o][m] = bf16( sum_d emb[m][d] * rk[r][d][o] )   (transposed)
// grid (64, 8), block 256. fp32 compute, LDS tiled.  (unchanged, verified)
// ---------------------------------------------------------------------------
__global__ __launch_bounds__(256) void compute_wt(const float* __restrict__ emb,
                                                  const float* __restrict__ rk,
                                                  ushort_t* __restrict__ Wt) {
  __shared__ float e_s[64][132];
  __shared__ float k_s[128][36];
  const int r  = blockIdx.y;
  const int m0 = blockIdx.x * 64;
  const int t  = threadIdx.x;
  {
    const int row = t >> 2, q = t & 3;
    const float* src = emb + (size_t)(m0 + row) * DD;
    #pragma unroll
    for (int j = 0; j < 8; ++j) {
      const int c = q + 4 * j;
      *(float4*)&e_s[row][c * 4] = *(const float4*)(src + c * 4);
    }
  }
  const int m_l = t >> 2, ob = (t & 3) * 8;
  const float* rkr = rk + (size_t)r * DD * OUTD;
  #pragma unroll 1
  for (int oc = 0; oc < 4; ++oc) {
    __syncthreads();
    {
      const int d = t >> 1, h = (t & 1) * 4;
      #pragma unroll
      for (int j = 0; j < 4; ++j) {
        const int c = h + j;
        *(float4*)&k_s[d][c * 4] = *(const float4*)(rkr + d * OUTD + oc * 32 + c * 4);
      }
    }
    __syncthreads();
    float acc[8] = {0, 0, 0, 0, 0, 0, 0, 0};
    #pragma unroll 4
    for (int d = 0; d < DD; ++d) {
      const float e  = e_s[m_l][d];
      const float4 w0 = *(const float4*)&k_s[d][ob];
      const float4 w1 = *(const float4*)&k_s[d][ob + 4];
      acc[0] += e * w0.x; acc[1] += e * w0.y; acc[2] += e * w0.z; acc[3] += e * w0.w;
      acc[4] += e * w1.x; acc[5] += e * w1.y; acc[6] += e * w1.z; acc[7] += e * w1.w;
    }
    ushort_t* dst = Wt + ((size_t)r * OUTD + oc * 32 + ob) * NN + m0 + m_l;
    #pragma unroll
    for (int j = 0; j < 8; ++j) dst[(size_t)j * NN] = f2bf(acc[j]);
  }
}

// ---------------------------------------------------------------------------
// Kernel B: Zc[r][ci][o] = adj[r][rows[ci]][:] @ Wt[r]   (bf16 MFMA, full K)
// grid 512: r = bid&7 (XCD-local r -> Wt[r] fits per-XCD L2), tile = bid>>3.
// block 256 = 4 waves; wave w owns output rows w*16..+15, all 128 cols.
// BK=64; BOTH A (fp32) and B (bf16) staged via coalesced global_load_lds into
// XOR-swizzled LDS (pre-swizzled global source, swizzled read; rule #21).
// 64 KB LDS -> 2 blocks/CU. 2-phase pipeline, one barrier per K-step.
// ---------------------------------------------------------------------------
__global__ __launch_bounds__(256, 2) void rgcn_main(const float* __restrict__ adj,
                                                    const ushort_t* __restrict__ Wt,
                                                    float* __restrict__ Zc,
                                                    const int* __restrict__ cntp,
                                                    const int* __restrict__ rowsp) {
  __shared__ floatx4 A4[2][1024];   // 64 rows x 16 chunks fp32  = 2 x 16 KB
  __shared__ short8  B8[2][1024];   // 128 rows x  8 chunks bf16 = 2 x 16 KB
  const int cnt = cntp[0];
  const int bid = blockIdx.x;
  const int r   = bid & 7;
  const int ci0 = (bid >> 3) * 64;
  if (ci0 >= cnt) return;
  const int t = threadIdx.x;
  const int lane = t & 63, wave = t >> 6;
  const int l15 = lane & 15, l4 = lane >> 4;
  const float*    __restrict__ adjr = adj + (size_t)r * NN * NN;
  const ushort_t* __restrict__ wtr  = Wt + (size_t)r * OUTD * NN;

  // precompute per-lane staging sources (swizzle folded into global addr)
  const float*    abase[4];
  const ushort_t* bbase[4];
  #pragma unroll
  for (int it = 0; it < 4; ++it) {
    const int s  = it * 256 + wave * 64 + lane;
    { // A: slot (row=s>>4, c=s&15) holds global chunk c^(row&15)
      const int rw = s >> 4, c = s & 15;
      const int ci = ci0 + rw;
      const int grow = (ci < cnt) ? rowsp[ci] : rowsp[ci0];  // safe dup for pad
      abase[it] = adjr + (size_t)grow * NN + (c ^ (rw & 15)) * 4;
    }
    { // B: slot (row=s>>3, c=s&7) holds global chunk c^(row&7)
      const int rw = s >> 3, c = s & 7;
      bbase[it] = wtr + (size_t)rw * NN + (c ^ (rw & 7)) * 8;
    }
  }

  auto stageA = [&](int buf, int k0) {
    #pragma unroll
    for (int it = 0; it < 4; ++it)
      __builtin_amdgcn_global_load_lds(
          (const __attribute__((address_space(1))) void*)(abase[it] + k0),
          (__attribute__((address_space(3))) void*)&A4[buf][it * 256 + wave * 64],
          16, 0, 0);
  };
  auto stageB = [&](int buf, int k0) {
    #pragma unroll
    for (int it = 0; it < 4; ++it)
      __builtin_amdgcn_global_load_lds(
          (const __attribute__((address_space(1))) void*)(bbase[it] + k0),
          (__attribute__((address_space(3))) void*)&B8[buf][it * 256 + wave * 64],
          16, 0, 0);
  };

  floatx4 acc[8] = {};
  stageA(0, 0); stageB(0, 0);
  __syncthreads();

  const int lrow = wave * 16 + l15;  // this lane's A row (local)
  int cur = 0;
  #pragma unroll 1
  for (int kt = 0; kt < 64; ++kt) {
    if (kt + 1 < 64) { stageA(cur ^ 1, (kt + 1) * 64); stageB(cur ^ 1, (kt + 1) * 64); }
    #pragma unroll
    for (int kk = 0; kk < 2; ++kk) {
      const int cc = kk * 8 + l4 * 2;  // fp32 chunk pair for k = kk*32+l4*8..+7
      const floatx4 alo = A4[cur][lrow * 16 + ((cc)     ^ (lrow & 15))];
      const floatx4 ahi = A4[cur][lrow * 16 + ((cc + 1) ^ (lrow & 15))];
      const short8 af = pack8(alo, ahi);
      #pragma unroll
      for (int tj = 0; tj < 8; ++tj) {
        const int orow = tj * 16 + l15;
        const short8 bf = B8[cur][orow * 8 + ((kk * 4 + l4) ^ (orow & 7))];
        acc[tj] = __builtin_amdgcn_mfma_f32_16x16x32_bf16(af, bf, acc[tj], 0, 0, 0);
      }
    }
    __syncthreads();   // drains next-tile prefetch (issued one compute-phase ago)
    cur ^= 1;
  }

  float* zout = Zc + ((size_t)r * NN + ci0 + wave * 16) * OUTD;
  #pragma unroll
  for (int tj = 0; tj < 8; ++tj)
    #pragma unroll
    for (int j = 0; j < 4; ++j)
      zout[(size_t)(l4 * 4 + j) * OUTD + tj * 16 + l15] = acc[tj][j];
}

// ---------------------------------------------------------------------------
// Kernel C: out[branch][b][o] = e[b]@self_kernel + sum_r Zc[r][inv[idx[b]]][o]
// grid 128: branch = x>>6, row tile = (x&63)*64. block 256.
// ---------------------------------------------------------------------------
__global__ __launch_bounds__(256) void epilogue_k(const float* __restrict__ he,
                                                  const float* __restrict__ te,
                                                  const int* __restrict__ hidx,
                                                  const int* __restrict__ tidx,
                                                  const float* __restrict__ sk,
                                                  const float* __restrict__ Zc,
                                                  const int* __restrict__ invp,
                                                  float* __restrict__ out) {
  __shared__ float e_s[64][132];
  __shared__ float k_s[128][36];
  const int bx = blockIdx.x;
  const int branch = bx >> 6;
  const int row0 = (bx & 63) * 64;
  const float* e  = branch ? te : he;
  const int* idx  = branch ? tidx : hidx;
  float* ob = out + (size_t)branch * BB * OUTD;
  const int t = threadIdx.x;
  {
    const int row = t >> 2, q = t & 3;
    const float* src = e + (size_t)(row0 + row) * DD;
    #pragma unroll
    for (int j = 0; j < 8; ++j) {
      const int c = q + 4 * j;
      *(float4*)&e_s[row][c * 4] = *(const float4*)(src + c * 4);
    }
  }
  const int m_l = t >> 2, obk = (t & 3) * 8;
  const int zi = idx[row0 + m_l];
  const int ci = invp[zi];
  #pragma unroll 1
  for (int oc = 0; oc < 4; ++oc) {
    __syncthreads();
    {
      const int d = t >> 1, h = (t & 1) * 4;
      #pragma unroll
      for (int j = 0; j < 4; ++j) {
        const int c = h + j;
        *(float4*)&k_s[d][c * 4] = *(const float4*)(sk + d * OUTD + oc * 32 + c * 4);
      }
    }
    __syncthreads();
    float acc[8] = {0, 0, 0, 0, 0, 0, 0, 0};
    #pragma unroll 4
    for (int d = 0; d < DD; ++d) {
      const float ev = e_s[m_l][d];
      const float4 w0 = *(const float4*)&k_s[d][obk];
      const float4 w1 = *(const float4*)&k_s[d][obk + 4];
      acc[0] += ev * w0.x; acc[1] += ev * w0.y; acc[2] += ev * w0.z; acc[3] += ev * w0.w;
      acc[4] += ev * w1.x; acc[5] += ev * w1.y; acc[6] += ev * w1.z; acc[7] += ev * w1.w;
    }
    floatx4 z0 = {0.f, 0.f, 0.f, 0.f}, z1 = {0.f, 0.f, 0.f, 0.f};
    #pragma unroll
    for (int rr = 0; rr < RR; ++rr) {
      const float* zrow = Zc + ((size_t)rr * NN + ci) * OUTD + oc * 32;
      z0 += *(const floatx4*)(zrow + obk);
      z1 += *(const floatx4*)(zrow + obk + 4);
    }
    floatx4 o0, o1;
    o0[0] = acc[0] + z0[0]; o0[1] = acc[1] + z0[1];
    o0[2] = acc[2] + z0[2]; o0[3] = acc[3] + z0[3];
    o1[0] = acc[4] + z1[0]; o1[1] = acc[5] + z1[1];
    o1[2] = acc[6] + z1[2]; o1[3] = acc[7] + z1[3];
    *(floatx4*)&ob[(size_t)(row0 + m_l) * OUTD + oc * 32 + obk]     = o0;
    *(floatx4*)&ob[(size_t)(row0 + m_l) * OUTD + oc * 32 + obk + 4] = o1;
  }
}

extern "C" void kernel_launch(void* const* d_in, const int* in_sizes, int n_in,
                              void* d_out, int out_size, void* d_ws, size_t ws_size,
                              hipStream_t stream) {
  const float* emb  = (const float*)d_in[0];
  const int*   hidx = (const int*)  d_in[1];
  const float* he   = (const float*)d_in[2];
  const int*   tidx = (const int*)  d_in[3];
  const float* te   = (const float*)d_in[4];
  const float* adj  = (const float*)d_in[5];
  const float* rk   = (const float*)d_in[6];
  const float* sk   = (const float*)d_in[7];
  float* out = (float*)d_out;

  // ws: [0,8MB) Wt bf16; [8MB,24MB) Zc fp32; [24MB,...) meta {cnt, rows, inv, flags}
  ushort_t* Wt = (ushort_t*)d_ws;
  float*    Zc = (float*)((char*)d_ws + (size_t)RR * OUTD * NN * sizeof(ushort_t));
  int* meta  = (int*)((char*)d_ws + (size_t)24 * 1024 * 1024);
  int* cnt   = meta;
  int* rows  = meta + 16;
  int* inv   = rows + NN;
  int* flags = inv + NN;

  build_rows<<<dim3(1), 1024, 0, stream>>>(hidx, tidx, cnt, rows, inv, flags);
  compute_wt<<<dim3(64, 8), 256, 0, stream>>>(emb, rk, Wt);
  rgcn_main<<<dim3(512), 256, 0, stream>>>(adj, Wt, Zc, cnt, rows);
  epilogue_k<<<dim3(128), 256, 0, stream>>>(he, te, hidx, tidx, sk, Zc, inv, out);
}

// Round 3
// 766.320 us; speedup vs baseline: 1.0006x; 1.0006x over previous
//
#include <hip/hip_runtime.h>

#define NN   4096
#define DD   128
#define RR   8
#define OUTD 128
#define BB   4096

typedef unsigned short ushort_t;
typedef __attribute__((ext_vector_type(8))) short short8;
typedef __attribute__((ext_vector_type(4))) float floatx4;

__device__ __forceinline__ ushort_t f2bf(float f) {
  union { float f; unsigned int u; } v; v.f = f;
  unsigned int u = v.u;
  return (ushort_t)((u + 0x7fffu + ((u >> 16) & 1u)) >> 16);  // RNE
}

__device__ __forceinline__ unsigned int pk2(float x, float y) {
  union { float f; unsigned int u; } a, b;
  a.f = x; b.f = y;
  const unsigned int ua = a.u + 0x8000u;
  const unsigned int ub = b.u + 0x8000u;
  return __builtin_amdgcn_perm(ub, ua, 0x07060302u);
}

__device__ __forceinline__ short8 pack8(floatx4 a, floatx4 b) {
  union { unsigned int u[4]; short8 s; } r;
  r.u[0] = pk2(a[0], a[1]); r.u[1] = pk2(a[2], a[3]);
  r.u[2] = pk2(b[0], b[1]); r.u[3] = pk2(b[2], b[3]);
  return r.s;
}

// ---------------------------------------------------------------------------
// Kernel 0: compacted row list = unique(head_idx ∪ tail_idx).
// 1 block, 1024 threads; flags cleared in-kernel (ws poisoned each iter).
// ---------------------------------------------------------------------------
__global__ __launch_bounds__(1024) void build_rows(const int* __restrict__ hidx,
                                                   const int* __restrict__ tidx,
                                                   int* __restrict__ cnt,
                                                   int* __restrict__ rows,
                                                   int* __restrict__ inv,
                                                   int* __restrict__ flags) {
  __shared__ int lcnt;
  const int t = threadIdx.x;
  if (t == 0) lcnt = 0;
  #pragma unroll
  for (int j = 0; j < 4; ++j) flags[t + j * 1024] = 0;
  __syncthreads();
  #pragma unroll
  for (int j = 0; j < 4; ++j) {
    flags[hidx[t + j * 1024]] = 1;   // benign races: all write 1
    flags[tidx[t + j * 1024]] = 1;
  }
  __syncthreads();
  #pragma unroll
  for (int j = 0; j < 4; ++j) {
    const int rrow = t + j * 1024;
    if (flags[rrow]) {
      const int p = atomicAdd(&lcnt, 1);
      rows[p]   = rrow;
      inv[rrow] = p;
    }
  }
  __syncthreads();
  if (t == 0) *cnt = lcnt;
}

// ---------------------------------------------------------------------------
// Kernel A: Wt[r][o][m] = bf16( sum_d emb[m][d] * rk[r][d][o] )   (transposed)
// grid (64, 8), block 256. fp32 compute, LDS tiled.  (verified, unchanged)
// ---------------------------------------------------------------------------
__global__ __launch_bounds__(256) void compute_wt(const float* __restrict__ emb,
                                                  const float* __restrict__ rk,
                                                  ushort_t* __restrict__ Wt) {
  __shared__ float e_s[64][132];
  __shared__ float k_s[128][36];
  const int r  = blockIdx.y;
  const int m0 = blockIdx.x * 64;
  const int t  = threadIdx.x;
  {
    const int row = t >> 2, q = t & 3;
    const float* src = emb + (size_t)(m0 + row) * DD;
    #pragma unroll
    for (int j = 0; j < 8; ++j) {
      const int c = q + 4 * j;
      *(float4*)&e_s[row][c * 4] = *(const float4*)(src + c * 4);
    }
  }
  const int m_l = t >> 2, ob = (t & 3) * 8;
  const float* rkr = rk + (size_t)r * DD * OUTD;
  #pragma unroll 1
  for (int oc = 0; oc < 4; ++oc) {
    __syncthreads();
    {
      const int d = t >> 1, h = (t & 1) * 4;
      #pragma unroll
      for (int j = 0; j < 4; ++j) {
        const int c = h + j;
        *(float4*)&k_s[d][c * 4] = *(const float4*)(rkr + d * OUTD + oc * 32 + c * 4);
      }
    }
    __syncthreads();
    float acc[8] = {0, 0, 0, 0, 0, 0, 0, 0};
    #pragma unroll 4
    for (int d = 0; d < DD; ++d) {
      const float e  = e_s[m_l][d];
      const float4 w0 = *(const float4*)&k_s[d][ob];
      const float4 w1 = *(const float4*)&k_s[d][ob + 4];
      acc[0] += e * w0.x; acc[1] += e * w0.y; acc[2] += e * w0.z; acc[3] += e * w0.w;
      acc[4] += e * w1.x; acc[5] += e * w1.y; acc[6] += e * w1.z; acc[7] += e * w1.w;
    }
    ushort_t* dst = Wt + ((size_t)r * OUTD + oc * 32 + ob) * NN + m0 + m_l;
    #pragma unroll
    for (int j = 0; j < 8; ++j) dst[(size_t)j * NN] = f2bf(acc[j]);
  }
}

// ---------------------------------------------------------------------------
// Kernel B (round-1 structure + compaction):
// Zc[r][ci][o] = adj[r][rows[ci]][:] @ Wt[r]   (bf16 MFMA, full K, BK=128)
// grid (64, 8): x = compacted-row tile (64), y = r; tiles past cnt exit.
// block 256 = 4 waves; wave w owns output rows w*16..+15, all 128 cols.
// - B tile (Wt, 128x128 bf16) double-buffered LDS via global_load_lds,
//   XOR-swizzled (pre-swizzled global source, swizzled read).
// - A rows per-lane straight from global (nontemporal, no LDS round-trip).
// - 2-phase pipeline, ONE barrier per K-step (32 total).
// ---------------------------------------------------------------------------
__global__ __launch_bounds__(256, 2) void rgcn_main(const float* __restrict__ adj,
                                                    const ushort_t* __restrict__ Wt,
                                                    float* __restrict__ Zc,
                                                    const int* __restrict__ cntp,
                                                    const int* __restrict__ rowsp) {
  __shared__ short8 B8[2][2048];   // 2 x (128 o-rows x 16 chunks) = 2 x 32 KB
  const int cnt = cntp[0];
  const int r   = blockIdx.y;
  const int ci0 = blockIdx.x * 64;
  if (ci0 >= cnt) return;
  const int t = threadIdx.x;
  const int lane = t & 63, wave = t >> 6;
  const int l15 = lane & 15, l4 = lane >> 4;           // l4 in 0..3
  // this lane's A row (compacted gather; clamp duplicates the last valid row)
  const int ci   = ci0 + wave * 16 + l15;
  const int grow = rowsp[ci < cnt ? ci : cnt - 1];
  const float* __restrict__ arow = adj + (size_t)r * NN * NN + (size_t)grow * NN;
  const ushort_t* __restrict__ wtr = Wt + (size_t)r * OUTD * NN;

  floatx4 acc[8] = {};   // 8 col-tiles of 16
  floatx4 av[8];         // A k-tile fp32: kk*32 + l4*8 .. +8 for kk=0..3
  short8  af[4];         // packed bf16 A fragments

  auto stageB = [&](int buf, int k0) {
    #pragma unroll
    for (int it = 0; it < 8; ++it) {
      const int s = wave * 512 + it * 64 + lane;
      const int o = s >> 4, kc = s & 15;
      const int gkc = kc ^ (o & 15);                   // pre-swizzle global addr
      const ushort_t* gp = wtr + (size_t)o * NN + k0 + gkc * 8;
      __builtin_amdgcn_global_load_lds(
          (const __attribute__((address_space(1))) void*)gp,
          (__attribute__((address_space(3))) void*)&B8[buf][wave * 512 + it * 64],
          16, 0, 0);
    }
  };
  auto loadA = [&](int k0) {
    #pragma unroll
    for (int kk = 0; kk < 4; ++kk) {
      const floatx4* p = (const floatx4*)(arow + k0 + kk * 32 + l4 * 8);
      av[2 * kk]     = __builtin_nontemporal_load(p);
      av[2 * kk + 1] = __builtin_nontemporal_load(p + 1);
    }
  };

  // prologue: stage tile 0, load A tile 0; syncthreads drains vmcnt(0)
  stageB(0, 0);
  loadA(0);
  __syncthreads();

  int cur = 0;
  #pragma unroll 1
  for (int kt = 0; kt < 32; ++kt) {
    // issue next B stage first (these gate the end-of-iter barrier)
    if (kt + 1 < 32) stageB(cur ^ 1, (kt + 1) * 128);
    // pack current A (consumes av), then issue next A loads into av
    #pragma unroll
    for (int kk = 0; kk < 4; ++kk) af[kk] = pack8(av[2 * kk], av[2 * kk + 1]);
    if (kt + 1 < 32) loadA((kt + 1) * 128);
    // compute on current buffer: 32 ds_read_b128 + 32 MFMA per wave
    #pragma unroll
    for (int kk = 0; kk < 4; ++kk) {
      short8 bf[8];
      #pragma unroll
      for (int tj = 0; tj < 8; ++tj) {
        const int orow = tj * 16 + l15;
        bf[tj] = B8[cur][orow * 16 + ((kk * 4 + l4) ^ (orow & 15))];
      }
      #pragma unroll
      for (int tj = 0; tj < 8; ++tj)
        acc[tj] = __builtin_amdgcn_mfma_f32_16x16x32_bf16(af[kk], bf[tj],
                                                          acc[tj], 0, 0, 0);
    }
    __syncthreads();   // drains the prefetch (issued one compute-phase ago)
    cur ^= 1;
  }

  // epilogue: plain coalesced stores of the per-r partial (compacted rows)
  float* zout = Zc + ((size_t)r * NN + ci0 + wave * 16) * OUTD;
  #pragma unroll
  for (int tj = 0; tj < 8; ++tj)
    #pragma unroll
    for (int j = 0; j < 4; ++j)
      zout[(size_t)(l4 * 4 + j) * OUTD + tj * 16 + l15] = acc[tj][j];
}

// ---------------------------------------------------------------------------
// Kernel C: out[branch][b][o] = e[b]@self_kernel + sum_r Zc[r][inv[idx[b]]][o]
// grid 128: branch = x>>6, row tile = (x&63)*64. block 256.
// ---------------------------------------------------------------------------
__global__ __launch_bounds__(256) void epilogue_k(const float* __restrict__ he,
                                                  const float* __restrict__ te,
                                                  const int* __restrict__ hidx,
                                                  const int* __restrict__ tidx,
                                                  const float* __restrict__ sk,
                                                  const float* __restrict__ Zc,
                                                  const int* __restrict__ invp,
                                                  float* __restrict__ out) {
  __shared__ float e_s[64][132];
  __shared__ float k_s[128][36];
  const int bx = blockIdx.x;
  const int branch = bx >> 6;
  const int row0 = (bx & 63) * 64;
  const float* e  = branch ? te : he;
  const int* idx  = branch ? tidx : hidx;
  float* ob = out + (size_t)branch * BB * OUTD;
  const int t = threadIdx.x;
  {
    const int row = t >> 2, q = t & 3;
    const float* src = e + (size_t)(row0 + row) * DD;
    #pragma unroll
    for (int j = 0; j < 8; ++j) {
      const int c = q + 4 * j;
      *(float4*)&e_s[row][c * 4] = *(const float4*)(src + c * 4);
    }
  }
  const int m_l = t >> 2, obk = (t & 3) * 8;
  const int zi = idx[row0 + m_l];
  const int ci = invp[zi];
  #pragma unroll 1
  for (int oc = 0; oc < 4; ++oc) {
    __syncthreads();
    {
      const int d = t >> 1, h = (t & 1) * 4;
      #pragma unroll
      for (int j = 0; j < 4; ++j) {
        const int c = h + j;
        *(float4*)&k_s[d][c * 4] = *(const float4*)(sk + d * OUTD + oc * 32 + c * 4);
      }
    }
    __syncthreads();
    float acc[8] = {0, 0, 0, 0, 0, 0, 0, 0};
    #pragma unroll 4
    for (int d = 0; d < DD; ++d) {
      const float ev = e_s[m_l][d];
      const float4 w0 = *(const float4*)&k_s[d][obk];
      const float4 w1 = *(const float4*)&k_s[d][obk + 4];
      acc[0] += ev * w0.x; acc[1] += ev * w0.y; acc[2] += ev * w0.z; acc[3] += ev * w0.w;
      acc[4] += ev * w1.x; acc[5] += ev * w1.y; acc[6] += ev * w1.z; acc[7] += ev * w1.w;
    }
    floatx4 z0 = {0.f, 0.f, 0.f, 0.f}, z1 = {0.f, 0.f, 0.f, 0.f};
    #pragma unroll
    for (int rr = 0; rr < RR; ++rr) {
      const float* zrow = Zc + ((size_t)rr * NN + ci) * OUTD + oc * 32;
      z0 += *(const floatx4*)(zrow + obk);
      z1 += *(const floatx4*)(zrow + obk + 4);
    }
    floatx4 o0, o1;
    o0[0] = acc[0] + z0[0]; o0[1] = acc[1] + z0[1];
    o0[2] = acc[2] + z0[2]; o0[3] = acc[3] + z0[3];
    o1[0] = acc[4] + z1[0]; o1[1] = acc[5] + z1[1];
    o1[2] = acc[6] + z1[2]; o1[3] = acc[7] + z1[3];
    *(floatx4*)&ob[(size_t)(row0 + m_l) * OUTD + oc * 32 + obk]     = o0;
    *(floatx4*)&ob[(size_t)(row0 + m_l) * OUTD + oc * 32 + obk + 4] = o1;
  }
}

extern "C" void kernel_launch(void* const* d_in, const int* in_sizes, int n_in,
                              void* d_out, int out_size, void* d_ws, size_t ws_size,
                              hipStream_t stream) {
  const float* emb  = (const float*)d_in[0];
  const int*   hidx = (const int*)  d_in[1];
  const float* he   = (const float*)d_in[2];
  const int*   tidx = (const int*)  d_in[3];
  const float* te   = (const float*)d_in[4];
  const float* adj  = (const float*)d_in[5];
  const float* rk   = (const float*)d_in[6];
  const float* sk   = (const float*)d_in[7];
  float* out = (float*)d_out;

  // ws: [0,8MB) Wt bf16; [8MB,24MB) Zc fp32; [24MB,...) meta {cnt, rows, inv, flags}
  ushort_t* Wt = (ushort_t*)d_ws;
  float*    Zc = (float*)((char*)d_ws + (size_t)RR * OUTD * NN * sizeof(ushort_t));
  int* meta  = (int*)((char*)d_ws + (size_t)24 * 1024 * 1024);
  int* cnt   = meta;
  int* rows  = meta + 16;
  int* inv   = rows + NN;
  int* flags = inv + NN;

  build_rows<<<dim3(1), 1024, 0, stream>>>(hidx, tidx, cnt, rows, inv, flags);
  compute_wt<<<dim3(64, 8), 256, 0, stream>>>(emb, rk, Wt);
  rgcn_main<<<dim3(64, 8), 256, 0, stream>>>(adj, Wt, Zc, cnt, rows);
  epilogue_k<<<dim3(128), 256, 0, stream>>>(he, te, hidx, tidx, sk, Zc, inv, out);
}

// Round 4
// 748.776 us; speedup vs baseline: 1.0241x; 1.0234x over previous
//
#include <hip/hip_runtime.h>

#define NN   4096
#define DD   128
#define RR   8
#define OUTD 128
#define BB   4096

typedef unsigned short ushort_t;
typedef __attribute__((ext_vector_type(8))) short short8;
typedef __attribute__((ext_vector_type(4))) float floatx4;

__device__ __forceinline__ ushort_t f2bf(float f) {
  union { float f; unsigned int u; } v; v.f = f;
  unsigned int u = v.u;
  return (ushort_t)((u + 0x7fffu + ((u >> 16) & 1u)) >> 16);  // RNE
}

// pack two fp32 -> two bf16 (round-half-up) in one dword via v_perm_b32
__device__ __forceinline__ unsigned int pk2(float x, float y) {
  union { float f; unsigned int u; } a, b;
  a.f = x; b.f = y;
  const unsigned int ua = a.u + 0x8000u;
  const unsigned int ub = b.u + 0x8000u;
  return __builtin_amdgcn_perm(ub, ua, 0x07060302u);
}

__device__ __forceinline__ short8 pack8(floatx4 a, floatx4 b) {
  union { unsigned int u[4]; short8 s; } r;
  r.u[0] = pk2(a[0], a[1]); r.u[1] = pk2(a[2], a[3]);
  r.u[2] = pk2(b[0], b[1]); r.u[3] = pk2(b[2], b[3]);
  return r.s;
}

// ---------------------------------------------------------------------------
// Kernel A: Wt[r][o][m] = bf16( sum_d emb[m][d] * rk[r][d][o] )   (transposed)
// grid (64, 8), block 256. fp32 compute, LDS tiled.  (verified)
// ---------------------------------------------------------------------------
__global__ __launch_bounds__(256) void compute_wt(const float* __restrict__ emb,
                                                  const float* __restrict__ rk,
                                                  ushort_t* __restrict__ Wt) {
  __shared__ float e_s[64][132];
  __shared__ float k_s[128][36];
  const int r  = blockIdx.y;
  const int m0 = blockIdx.x * 64;
  const int t  = threadIdx.x;
  {
    const int row = t >> 2, q = t & 3;
    const float* src = emb + (size_t)(m0 + row) * DD;
    #pragma unroll
    for (int j = 0; j < 8; ++j) {
      const int c = q + 4 * j;
      *(float4*)&e_s[row][c * 4] = *(const float4*)(src + c * 4);
    }
  }
  const int m_l = t >> 2, ob = (t & 3) * 8;
  const float* rkr = rk + (size_t)r * DD * OUTD;
  #pragma unroll 1
  for (int oc = 0; oc < 4; ++oc) {
    __syncthreads();
    {
      const int d = t >> 1, h = (t & 1) * 4;
      #pragma unroll
      for (int j = 0; j < 4; ++j) {
        const int c = h + j;
        *(float4*)&k_s[d][c * 4] = *(const float4*)(rkr + d * OUTD + oc * 32 + c * 4);
      }
    }
    __syncthreads();
    float acc[8] = {0, 0, 0, 0, 0, 0, 0, 0};
    #pragma unroll 4
    for (int d = 0; d < DD; ++d) {
      const float e  = e_s[m_l][d];
      const float4 w0 = *(const float4*)&k_s[d][ob];
      const float4 w1 = *(const float4*)&k_s[d][ob + 4];
      acc[0] += e * w0.x; acc[1] += e * w0.y; acc[2] += e * w0.z; acc[3] += e * w0.w;
      acc[4] += e * w1.x; acc[5] += e * w1.y; acc[6] += e * w1.z; acc[7] += e * w1.w;
    }
    ushort_t* dst = Wt + ((size_t)r * OUTD + oc * 32 + ob) * NN + m0 + m_l;
    #pragma unroll
    for (int j = 0; j < 8; ++j) dst[(size_t)j * NN] = f2bf(acc[j]);
  }
}

// ---------------------------------------------------------------------------
// Kernel B: Zr[r][n][o] = adj[r][n0..][0..4096] @ Wt[r]   (bf16 MFMA, full K)
// grid (64, 8): x = n-tile (64 rows), y = r. block 256 = 4 waves (4x1 layout:
// wave w owns output rows w*16..w*16+15, all 128 cols).
// - B tile (Wt, 128x128 bf16) double-buffered in LDS via global_load_lds,
//   XOR-swizzled 16B chunks (pre-swizzled global source, swizzled read).
// - A (adj rows) loaded per-lane straight into MFMA fragment rows (no LDS),
//   nontemporal so the 512MB adj stream doesn't evict Wt from L2.
// - minimum 2-phase pipeline: STAGE(next) before compute, ONE barrier/K-step.
// - no split-K -> no atomics, no memset; plain per-r partial stores.
// Best-measured variant (R1: 751.5 us total window). Compaction (R2/R3) and
// LDS-staged A (R2) both measured net-negative; do not re-add.
// ---------------------------------------------------------------------------
__global__ __launch_bounds__(256, 2) void rgcn_main(const float* __restrict__ adj,
                                                    const ushort_t* __restrict__ Wt,
                                                    float* __restrict__ Zr) {
  __shared__ short8 B8[2][2048];   // 2 x (128 o-rows x 16 chunks) = 2 x 32 KB
  const int r  = blockIdx.y;
  const int n0 = blockIdx.x * 64;
  const int t = threadIdx.x;
  const int lane = t & 63, wave = t >> 6;
  const int l15 = lane & 15, l4 = lane >> 4;           // l4 in 0..3
  const float* __restrict__ arow =
      adj + (size_t)r * NN * NN + (size_t)(n0 + wave * 16 + l15) * NN;
  const ushort_t* __restrict__ wtr = Wt + (size_t)r * OUTD * NN;

  floatx4 acc[8] = {};   // 8 col-tiles of 16
  floatx4 av[8];         // A k-tile fp32: kk*32 + l4*8 .. +8 for kk=0..3
  short8  af[4];         // packed bf16 A fragments

  auto stageB = [&](int buf, int k0) {
    #pragma unroll
    for (int it = 0; it < 8; ++it) {
      const int s = wave * 512 + it * 64 + lane;
      const int o = s >> 4, kc = s & 15;
      const int gkc = kc ^ (o & 15);                   // pre-swizzle global addr
      const ushort_t* gp = wtr + (size_t)o * NN + k0 + gkc * 8;
      __builtin_amdgcn_global_load_lds(
          (const __attribute__((address_space(1))) void*)gp,
          (__attribute__((address_space(3))) void*)&B8[buf][wave * 512 + it * 64],
          16, 0, 0);
    }
  };
  auto loadA = [&](int k0) {
    #pragma unroll
    for (int kk = 0; kk < 4; ++kk) {
      const floatx4* p = (const floatx4*)(arow + k0 + kk * 32 + l4 * 8);
      av[2 * kk]     = __builtin_nontemporal_load(p);
      av[2 * kk + 1] = __builtin_nontemporal_load(p + 1);
    }
  };

  // prologue: stage tile 0, load A tile 0; syncthreads drains vmcnt(0)
  stageB(0, 0);
  loadA(0);
  __syncthreads();

  int cur = 0;
  #pragma unroll 1
  for (int kt = 0; kt < 32; ++kt) {
    // issue next B stage first (these gate the end-of-iter barrier)
    if (kt + 1 < 32) stageB(cur ^ 1, (kt + 1) * 128);
    // pack current A (consumes av), then issue next A loads into av
    #pragma unroll
    for (int kk = 0; kk < 4; ++kk) af[kk] = pack8(av[2 * kk], av[2 * kk + 1]);
    if (kt + 1 < 32) loadA((kt + 1) * 128);
    // compute on current buffer: 32 ds_read_b128 + 32 MFMA per wave
    #pragma unroll
    for (int kk = 0; kk < 4; ++kk) {
      short8 bf[8];
      #pragma unroll
      for (int tj = 0; tj < 8; ++tj) {
        const int orow = tj * 16 + l15;
        bf[tj] = B8[cur][orow * 16 + ((kk * 4 + l4) ^ (orow & 15))];
      }
      #pragma unroll
      for (int tj = 0; tj < 8; ++tj)
        acc[tj] = __builtin_amdgcn_mfma_f32_16x16x32_bf16(af[kk], bf[tj],
                                                          acc[tj], 0, 0, 0);
    }
    __syncthreads();   // drains the prefetch (issued one compute-phase ago)
    cur ^= 1;
  }

  // epilogue: plain coalesced stores of the per-r partial
  float* zout = Zr + ((size_t)r * NN + n0 + wave * 16) * OUTD;
  #pragma unroll
  for (int tj = 0; tj < 8; ++tj)
    #pragma unroll
    for (int j = 0; j < 4; ++j)
      zout[(size_t)(l4 * 4 + j) * OUTD + tj * 16 + l15] = acc[tj][j];
}

// ---------------------------------------------------------------------------
// Kernel C: out[branch][b][o] = e[b]@self_kernel + sum_r Zr[r][idx[b]][o]
// grid 128: branch = x>>6, row tile = (x&63)*64. block 256.
// ---------------------------------------------------------------------------
__global__ __launch_bounds__(256) void epilogue_k(const float* __restrict__ he,
                                                  const float* __restrict__ te,
                                                  const int* __restrict__ hidx,
                                                  const int* __restrict__ tidx,
                                                  const float* __restrict__ sk,
                                                  const float* __restrict__ Zr,
                                                  float* __restrict__ out) {
  __shared__ float e_s[64][132];
  __shared__ float k_s[128][36];
  const int bx = blockIdx.x;
  const int branch = bx >> 6;
  const int row0 = (bx & 63) * 64;
  const float* e  = branch ? te : he;
  const int* idx  = branch ? tidx : hidx;
  float* ob = out + (size_t)branch * BB * OUTD;
  const int t = threadIdx.x;
  {
    const int row = t >> 2, q = t & 3;
    const float* src = e + (size_t)(row0 + row) * DD;
    #pragma unroll
    for (int j = 0; j < 8; ++j) {
      const int c = q + 4 * j;
      *(float4*)&e_s[row][c * 4] = *(const float4*)(src + c * 4);
    }
  }
  const int m_l = t >> 2, obk = (t & 3) * 8;
  const int zi = idx[row0 + m_l];
  #pragma unroll 1
  for (int oc = 0; oc < 4; ++oc) {
    __syncthreads();
    {
      const int d = t >> 1, h = (t & 1) * 4;
      #pragma unroll
      for (int j = 0; j < 4; ++j) {
        const int c = h + j;
        *(float4*)&k_s[d][c * 4] = *(const float4*)(sk + d * OUTD + oc * 32 + c * 4);
      }
    }
    __syncthreads();
    float acc[8] = {0, 0, 0, 0, 0, 0, 0, 0};
    #pragma unroll 4
    for (int d = 0; d < DD; ++d) {
      const float ev = e_s[m_l][d];
      const float4 w0 = *(const float4*)&k_s[d][obk];
      const float4 w1 = *(const float4*)&k_s[d][obk + 4];
      acc[0] += ev * w0.x; acc[1] += ev * w0.y; acc[2] += ev * w0.z; acc[3] += ev * w0.w;
      acc[4] += ev * w1.x; acc[5] += ev * w1.y; acc[6] += ev * w1.z; acc[7] += ev * w1.w;
    }
    // sum the 8 per-r partials (Zr is 16MB -> L2/L3 resident)
    floatx4 z0 = {0.f, 0.f, 0.f, 0.f}, z1 = {0.f, 0.f, 0.f, 0.f};
    #pragma unroll
    for (int rr = 0; rr < RR; ++rr) {
      const float* zrow = Zr + ((size_t)rr * NN + zi) * OUTD + oc * 32;
      z0 += *(const floatx4*)(zrow + obk);
      z1 += *(const floatx4*)(zrow + obk + 4);
    }
    floatx4 o0, o1;
    o0[0] = acc[0] + z0[0]; o0[1] = acc[1] + z0[1];
    o0[2] = acc[2] + z0[2]; o0[3] = acc[3] + z0[3];
    o1[0] = acc[4] + z1[0]; o1[1] = acc[5] + z1[1];
    o1[2] = acc[6] + z1[2]; o1[3] = acc[7] + z1[3];
    *(floatx4*)&ob[(size_t)(row0 + m_l) * OUTD + oc * 32 + obk]     = o0;
    *(floatx4*)&ob[(size_t)(row0 + m_l) * OUTD + oc * 32 + obk + 4] = o1;
  }
}

extern "C" void kernel_launch(void* const* d_in, const int* in_sizes, int n_in,
                              void* d_out, int out_size, void* d_ws, size_t ws_size,
                              hipStream_t stream) {
  const float* emb  = (const float*)d_in[0];
  const int*   hidx = (const int*)  d_in[1];
  const float* he   = (const float*)d_in[2];
  const int*   tidx = (const int*)  d_in[3];
  const float* te   = (const float*)d_in[4];
  const float* adj  = (const float*)d_in[5];
  const float* rk   = (const float*)d_in[6];
  const float* sk   = (const float*)d_in[7];
  float* out = (float*)d_out;

  // ws layout: [0, 8MB) Wt bf16 (R*OUT*N), [8MB, 24MB) Zr fp32 (R*N*OUT)
  ushort_t* Wt = (ushort_t*)d_ws;
  float*    Zr = (float*)((char*)d_ws + (size_t)RR * OUTD * NN * sizeof(ushort_t));

  compute_wt<<<dim3(64, 8), 256, 0, stream>>>(emb, rk, Wt);
  rgcn_main<<<dim3(64, 8), 256, 0, stream>>>(adj, Wt, Zr);
  epilogue_k<<<dim3(128), 256, 0, stream>>>(he, te, hidx, tidx, sk, Zr, out);
}